// Round 1
// baseline (301.289 us; speedup 1.0000x reference)
//
#include <hip/hip_runtime.h>

// SoftAttention: B=4, Q=64, S=1024, H=512, fp32.
// out = [context (B*Q*H)] ++ [weights (B*Q*S)]

constexpr int kB = 4;
constexpr int kQ = 64;
constexpr int kS = 1024;
constexpr int kH = 512;

__device__ __forceinline__ float fast_tanh(float x) {
  // tanh(x) = sign(x) * (1 - t) / (1 + t),  t = exp(-2|x|)  (no overflow)
  float ax = fabsf(x);
  float t = __expf(-2.f * ax);
  float r = (1.f - t) * __builtin_amdgcn_rcpf(1.f + t);
  return copysignf(r, x);
}

// Y[row, h] = sum_d X[row, d] * W[d, h] + bias[h]; TM rows per block.
template <int TM>
__global__ __launch_bounds__(256) void proj_kernel(
    const float* __restrict__ X, const float* __restrict__ W,
    const float* __restrict__ bias, float* __restrict__ Y) {
  __shared__ __align__(16) float xs[TM * kH];
  const int tid = threadIdx.x;
  const size_t row0 = (size_t)blockIdx.x * TM;

  const float4* xsrc = (const float4*)(X + row0 * kH);
  float4* xdst = (float4*)xs;
  for (int i = tid; i < TM * kH / 4; i += 256) xdst[i] = xsrc[i];
  __syncthreads();

  const int h = tid * 2;  // 256 threads x 2 cols = 512
  float2 acc[TM];
#pragma unroll
  for (int r = 0; r < TM; r++) { acc[r].x = 0.f; acc[r].y = 0.f; }

  for (int d = 0; d < kH; d += 4) {
    float2 w0 = *(const float2*)(W + (size_t)d * kH + h);
    float2 w1 = *(const float2*)(W + (size_t)(d + 1) * kH + h);
    float2 w2 = *(const float2*)(W + (size_t)(d + 2) * kH + h);
    float2 w3 = *(const float2*)(W + (size_t)(d + 3) * kH + h);
#pragma unroll
    for (int r = 0; r < TM; r++) {
      float4 xv = *(const float4*)(xs + r * kH + d);  // broadcast read
      acc[r].x = fmaf(xv.x, w0.x, acc[r].x); acc[r].y = fmaf(xv.x, w0.y, acc[r].y);
      acc[r].x = fmaf(xv.y, w1.x, acc[r].x); acc[r].y = fmaf(xv.y, w1.y, acc[r].y);
      acc[r].x = fmaf(xv.z, w2.x, acc[r].x); acc[r].y = fmaf(xv.z, w2.y, acc[r].y);
      acc[r].x = fmaf(xv.w, w3.x, acc[r].x); acc[r].y = fmaf(xv.w, w3.y, acc[r].y);
    }
  }

  float2 b2 = *(const float2*)(bias + h);
#pragma unroll
  for (int r = 0; r < TM; r++) {
    float2 o; o.x = acc[r].x + b2.x; o.y = acc[r].y + b2.y;
    *(float2*)(Y + (row0 + r) * kH + h) = o;
  }
}

// One block per (b,q). 512 threads = 8 waves.
__global__ __launch_bounds__(512) void attn_kernel(
    const float* __restrict__ qp, const float* __restrict__ kp,
    const float* __restrict__ value, const float* __restrict__ we,
    const float* __restrict__ be_p, float* __restrict__ ctx,
    float* __restrict__ wout) {
  __shared__ __align__(16) float sc[kS];
  __shared__ float red[8];
  const int tid = threadIdx.x;
  const int wave = tid >> 6;
  const int lane = tid & 63;
  const int bq = blockIdx.x;  // 0..255
  const int b = bq >> 6;      // kQ = 64
  const float be = *be_p;

  // Each lane owns h = lane*8 .. lane*8+7 (64 lanes * 8 = 512).
  const float4* qp4 = (const float4*)(qp + (size_t)bq * kH + lane * 8);
  const float4 q0 = qp4[0], q1 = qp4[1];
  const float4* we4 = (const float4*)(we + lane * 8);
  const float4 w0 = we4[0], w1 = we4[1];

  const float* kpb = kp + (size_t)b * kS * kH;
  for (int s = wave; s < kS; s += 8) {
    const float4* k4 = (const float4*)(kpb + (size_t)s * kH + lane * 8);
    float4 k0 = k4[0], k1 = k4[1];
    float p = 0.f;
    p = fmaf(w0.x, fast_tanh(q0.x + k0.x), p);
    p = fmaf(w0.y, fast_tanh(q0.y + k0.y), p);
    p = fmaf(w0.z, fast_tanh(q0.z + k0.z), p);
    p = fmaf(w0.w, fast_tanh(q0.w + k0.w), p);
    p = fmaf(w1.x, fast_tanh(q1.x + k1.x), p);
    p = fmaf(w1.y, fast_tanh(q1.y + k1.y), p);
    p = fmaf(w1.z, fast_tanh(q1.z + k1.z), p);
    p = fmaf(w1.w, fast_tanh(q1.w + k1.w), p);
#pragma unroll
    for (int off = 32; off; off >>= 1) p += __shfl_xor(p, off);
    if (lane == 0) sc[s] = p + be;
  }
  __syncthreads();

  // Softmax over sc[0..kS)
  float m = -3.0e38f;
  for (int i = tid; i < kS; i += 512) m = fmaxf(m, sc[i]);
#pragma unroll
  for (int off = 32; off; off >>= 1) m = fmaxf(m, __shfl_xor(m, off));
  if (lane == 0) red[wave] = m;
  __syncthreads();
  m = red[0];
#pragma unroll
  for (int w = 1; w < 8; w++) m = fmaxf(m, red[w]);

  float sum = 0.f;
  for (int i = tid; i < kS; i += 512) {
    float e = __expf(sc[i] - m);
    sc[i] = e;
    sum += e;
  }
#pragma unroll
  for (int off = 32; off; off >>= 1) sum += __shfl_xor(sum, off);
  __syncthreads();  // all reads of red (max) done before overwrite
  if (lane == 0) red[wave] = sum;
  __syncthreads();
  sum = red[0];
#pragma unroll
  for (int w = 1; w < 8; w++) sum += red[w];
  float inv = 1.f / sum;

  float* wrow = wout + (size_t)bq * kS;
  for (int i = tid; i < kS; i += 512) {
    float wgt = sc[i] * inv;
    sc[i] = wgt;
    wrow[i] = wgt;
  }
  __syncthreads();

  // context[h] = sum_s w[s] * value[b, s, h]; h = tid (512 threads).
  const float* vb = value + (size_t)b * kS * kH;
  float acc = 0.f;
#pragma unroll 8
  for (int s = 0; s < kS; s++) acc = fmaf(sc[s], vb[(size_t)s * kH + tid], acc);
  ctx[(size_t)bq * kH + tid] = acc;
}

extern "C" void kernel_launch(void* const* d_in, const int* in_sizes, int n_in,
                              void* d_out, int out_size, void* d_ws,
                              size_t ws_size, hipStream_t stream) {
  const float* query = (const float*)d_in[0];
  const float* key_  = (const float*)d_in[1];
  const float* value = (const float*)d_in[2];
  const float* Wq    = (const float*)d_in[3];
  const float* bq    = (const float*)d_in[4];
  const float* Wk    = (const float*)d_in[5];
  const float* bk    = (const float*)d_in[6];
  const float* we    = (const float*)d_in[7];
  const float* be    = (const float*)d_in[8];

  float* ctx  = (float*)d_out;                          // [B*Q*H]
  float* wout = (float*)d_out + (size_t)kB * kQ * kH;   // [B*Q*S]

  float* qp = (float*)d_ws;                      // 256*512 floats
  float* kp = qp + (size_t)kB * kQ * kH;         // 4096*512 floats

  proj_kernel<4><<<kB * kQ / 4, 256, 0, stream>>>(query, Wq, bq, qp);
  proj_kernel<16><<<kB * kS / 16, 256, 0, stream>>>(key_, Wk, bk, kp);
  attn_kernel<<<kB * kQ, 512, 0, stream>>>(qp, kp, value, we, be, ctx, wout);
}

// Round 2
// 269.288 us; speedup vs baseline: 1.1188x; 1.1188x over previous
//
#include <hip/hip_runtime.h>

// SoftAttention: B=4, Q=64, S=1024, H=512, fp32.
// out = [context (B*Q*H)] ++ [weights (B*Q*S)]
// ws layout: qp [256*512] at 0; kp [4096*512] at +512KB;
//            context partials [8][256*512] alias the (dead-after-score) kp region.

constexpr int kB = 4;
constexpr int kQ = 64;
constexpr int kS = 1024;
constexpr int kH = 512;

// ---------------------------------------------------------------------------
// Projection: Y[M,512] = X[M,512] @ W[512,512] + bias.  64x64 tile, 256 thr,
// 16 acc/thread (4 rows x 4 cols).  grid = (8 col-tiles, 64 kp-tiles + 4 qp-tiles)
// ---------------------------------------------------------------------------
__global__ __launch_bounds__(256) void proj_dual(
    const float* __restrict__ Xk, const float* __restrict__ Wk,
    const float* __restrict__ bk, float* __restrict__ Yk,
    const float* __restrict__ Xq, const float* __restrict__ Wq,
    const float* __restrict__ bq, float* __restrict__ Yq) {
  __shared__ __align__(16) float xs[64][68];  // stride 68 = 16B-aligned, 2-way bank alias (free)
  const int t = threadIdx.x;
  const int ct = blockIdx.x;  // 0..7
  int rt = blockIdx.y;        // 0..67
  const float *X, *W, *bias;
  float* Y;
  if (rt < 64) {
    X = Xk + (size_t)rt * 64 * kH; W = Wk; bias = bk; Y = Yk + (size_t)rt * 64 * kH;
  } else {
    rt -= 64;
    X = Xq + (size_t)rt * 64 * kH; W = Wq; bias = bq; Y = Yq + (size_t)rt * 64 * kH;
  }

  const int c = ct * 64 + (t & 15) * 4;   // 4 output cols
  const int r0 = (t >> 4) * 4;            // 4 output rows
  const int sr = t >> 2;                  // staging row
  const int sc4 = (t & 3) * 16;           // staging col start (16 floats)

  float4 acc0 = {0,0,0,0}, acc1 = {0,0,0,0}, acc2 = {0,0,0,0}, acc3 = {0,0,0,0};

  for (int kc = 0; kc < kH; kc += 64) {
    __syncthreads();
    const float4* src = (const float4*)(X + (size_t)sr * kH + kc + sc4);
    float4 s0 = src[0], s1 = src[1], s2 = src[2], s3 = src[3];
    *(float4*)&xs[sr][sc4 + 0]  = s0;
    *(float4*)&xs[sr][sc4 + 4]  = s1;
    *(float4*)&xs[sr][sc4 + 8]  = s2;
    *(float4*)&xs[sr][sc4 + 12] = s3;
    __syncthreads();

    const float* wp = W + (size_t)kc * kH + c;
#pragma unroll 16
    for (int kk = 0; kk < 64; kk++) {
      float4 wv = *(const float4*)(wp + (size_t)kk * kH);
      float x0 = xs[r0 + 0][kk];
      float x1 = xs[r0 + 1][kk];
      float x2 = xs[r0 + 2][kk];
      float x3 = xs[r0 + 3][kk];
      acc0.x = fmaf(x0, wv.x, acc0.x); acc0.y = fmaf(x0, wv.y, acc0.y);
      acc0.z = fmaf(x0, wv.z, acc0.z); acc0.w = fmaf(x0, wv.w, acc0.w);
      acc1.x = fmaf(x1, wv.x, acc1.x); acc1.y = fmaf(x1, wv.y, acc1.y);
      acc1.z = fmaf(x1, wv.z, acc1.z); acc1.w = fmaf(x1, wv.w, acc1.w);
      acc2.x = fmaf(x2, wv.x, acc2.x); acc2.y = fmaf(x2, wv.y, acc2.y);
      acc2.z = fmaf(x2, wv.z, acc2.z); acc2.w = fmaf(x2, wv.w, acc2.w);
      acc3.x = fmaf(x3, wv.x, acc3.x); acc3.y = fmaf(x3, wv.y, acc3.y);
      acc3.z = fmaf(x3, wv.z, acc3.z); acc3.w = fmaf(x3, wv.w, acc3.w);
    }
  }

  float4 bv = *(const float4*)(bias + c);
  acc0.x += bv.x; acc0.y += bv.y; acc0.z += bv.z; acc0.w += bv.w;
  acc1.x += bv.x; acc1.y += bv.y; acc1.z += bv.z; acc1.w += bv.w;
  acc2.x += bv.x; acc2.y += bv.y; acc2.z += bv.z; acc2.w += bv.w;
  acc3.x += bv.x; acc3.y += bv.y; acc3.z += bv.z; acc3.w += bv.w;
  *(float4*)(Y + (size_t)(r0 + 0) * kH + c) = acc0;
  *(float4*)(Y + (size_t)(r0 + 1) * kH + c) = acc1;
  *(float4*)(Y + (size_t)(r0 + 2) * kH + c) = acc2;
  *(float4*)(Y + (size_t)(r0 + 3) * kH + c) = acc3;
}

// ---------------------------------------------------------------------------
// Scores: raw (un-softmaxed) scores -> sout[bq][s].  be is dropped (cancels in
// softmax).  grid = 1024 (b x 16 q-tiles x 16 s-chunks), 256 thr = 4 waves.
// Each wave: 16 s, 4 q per s; lane owns h = lane*8..+7.
// tanh(x) = 1 - 2*d, d = rcp(1 + exp(2x));  sum we*tanh = sum_we - 2*sum we*d.
// ---------------------------------------------------------------------------
__global__ __launch_bounds__(256) void score_kernel(
    const float* __restrict__ qp, const float* __restrict__ kp,
    const float* __restrict__ we, float* __restrict__ sout) {
  const int bx = blockIdx.x;
  const int b = bx >> 8, qt = (bx >> 4) & 15, st = bx & 15;
  const int t = threadIdx.x, wave = t >> 6, lane = t & 63;

  const float4* we4 = (const float4*)(we + lane * 8);
  const float4 w0 = we4[0], w1 = we4[1];
  float wsum = w0.x + w0.y + w0.z + w0.w + w1.x + w1.y + w1.z + w1.w;
#pragma unroll
  for (int off = 32; off; off >>= 1) wsum += __shfl_xor(wsum, off);
  // wsum == total sum of we over all 512 h (same in every lane)

  const int q0 = qt * 4;
  float4 qv[4][2];
#pragma unroll
  for (int i = 0; i < 4; i++) {
    const float4* q4 = (const float4*)(qp + (size_t)(b * kQ + q0 + i) * kH + lane * 8);
    qv[i][0] = q4[0]; qv[i][1] = q4[1];
  }

  const float* kpb = kp + (size_t)b * kS * kH;
  const int sbase = st * 64 + wave * 16;

  for (int si = 0; si < 16; si++) {
    const int s = sbase + si;
    const float4* k4 = (const float4*)(kpb + (size_t)s * kH + lane * 8);
    float4 k0 = k4[0], k1 = k4[1];
    float a[4];
#pragma unroll
    for (int i = 0; i < 4; i++) {
      float acc = 0.f;
      float e;
      e = __expf(2.f * (qv[i][0].x + k0.x)); acc = fmaf(w0.x, __builtin_amdgcn_rcpf(1.f + e), acc);
      e = __expf(2.f * (qv[i][0].y + k0.y)); acc = fmaf(w0.y, __builtin_amdgcn_rcpf(1.f + e), acc);
      e = __expf(2.f * (qv[i][0].z + k0.z)); acc = fmaf(w0.z, __builtin_amdgcn_rcpf(1.f + e), acc);
      e = __expf(2.f * (qv[i][0].w + k0.w)); acc = fmaf(w0.w, __builtin_amdgcn_rcpf(1.f + e), acc);
      e = __expf(2.f * (qv[i][1].x + k1.x)); acc = fmaf(w1.x, __builtin_amdgcn_rcpf(1.f + e), acc);
      e = __expf(2.f * (qv[i][1].y + k1.y)); acc = fmaf(w1.y, __builtin_amdgcn_rcpf(1.f + e), acc);
      e = __expf(2.f * (qv[i][1].z + k1.z)); acc = fmaf(w1.z, __builtin_amdgcn_rcpf(1.f + e), acc);
      e = __expf(2.f * (qv[i][1].w + k1.w)); acc = fmaf(w1.w, __builtin_amdgcn_rcpf(1.f + e), acc);
      a[i] = acc;
    }
#pragma unroll
    for (int i = 0; i < 4; i++) {
#pragma unroll
      for (int off = 32; off; off >>= 1) a[i] += __shfl_xor(a[i], off);
    }
    if (lane == 0) {
#pragma unroll
      for (int i = 0; i < 4; i++)
        sout[(size_t)(b * kQ + q0 + i) * kS + s] = fmaf(-2.f, a[i], wsum);
    }
  }
}

// ---------------------------------------------------------------------------
// Softmax in place on wout rows of 1024.  grid = 256 rows, 256 thr (4 waves).
// ---------------------------------------------------------------------------
__global__ __launch_bounds__(256) void softmax_kernel(float* __restrict__ wout) {
  __shared__ float redm[4];
  __shared__ float reds[4];
  const int row = blockIdx.x;
  const int t = threadIdx.x, wave = t >> 6, lane = t & 63;
  float4* rp = (float4*)(wout + (size_t)row * kS);
  float4 v = rp[t];

  float m = fmaxf(fmaxf(v.x, v.y), fmaxf(v.z, v.w));
#pragma unroll
  for (int off = 32; off; off >>= 1) m = fmaxf(m, __shfl_xor(m, off));
  if (lane == 0) redm[wave] = m;
  __syncthreads();
  m = fmaxf(fmaxf(redm[0], redm[1]), fmaxf(redm[2], redm[3]));

  float4 e;
  e.x = __expf(v.x - m); e.y = __expf(v.y - m);
  e.z = __expf(v.z - m); e.w = __expf(v.w - m);
  float sum = e.x + e.y + e.z + e.w;
#pragma unroll
  for (int off = 32; off; off >>= 1) sum += __shfl_xor(sum, off);
  if (lane == 0) reds[wave] = sum;
  __syncthreads();
  sum = reds[0] + reds[1] + reds[2] + reds[3];
  float inv = 1.f / sum;
  e.x *= inv; e.y *= inv; e.z *= inv; e.w *= inv;
  rp[t] = e;
}

// ---------------------------------------------------------------------------
// Context partials: part[sc][bq][h] = sum_{s in chunk} w[bq][s] * value[b][s][h]
// grid = 256 (b x 2 h-chunks x 4 q-chunks x 8 s-chunks), 256 thr.
// ---------------------------------------------------------------------------
__global__ __launch_bounds__(256) void context_kernel(
    const float* __restrict__ wout, const float* __restrict__ value,
    float* __restrict__ part) {
  __shared__ __align__(16) float wt[128][16];
  const int bx = blockIdx.x;
  const int sc = bx & 7, qc = (bx >> 3) & 3, hc = (bx >> 5) & 1, b = bx >> 6;
  const int t = threadIdx.x;
  const int s0 = sc * 128, q0 = qc * 16;

  {  // load + transpose weights tile [16 q][128 s] -> wt[s][q]
    const int q_l = t & 15;         // 0..15
    const int sseg = (t >> 4) * 8;  // 0..120 step 8
    const float4* p4 =
        (const float4*)(wout + (size_t)(b * kQ + q0 + q_l) * kS + s0 + sseg);
    float4 u0 = p4[0], u1 = p4[1];
    wt[sseg + 0][q_l] = u0.x; wt[sseg + 1][q_l] = u0.y;
    wt[sseg + 2][q_l] = u0.z; wt[sseg + 3][q_l] = u0.w;
    wt[sseg + 4][q_l] = u1.x; wt[sseg + 5][q_l] = u1.y;
    wt[sseg + 6][q_l] = u1.z; wt[sseg + 7][q_l] = u1.w;
  }
  __syncthreads();

  const int h = hc * 256 + t;
  const float* vb = value + ((size_t)b * kS + s0) * kH + h;
  float acc[16];
#pragma unroll
  for (int i = 0; i < 16; i++) acc[i] = 0.f;

#pragma unroll 4
  for (int s = 0; s < 128; s++) {
    float v = vb[(size_t)s * kH];
    const float4* wrow = (const float4*)&wt[s][0];
    float4 a0 = wrow[0], a1 = wrow[1], a2 = wrow[2], a3 = wrow[3];
    acc[0]  = fmaf(a0.x, v, acc[0]);  acc[1]  = fmaf(a0.y, v, acc[1]);
    acc[2]  = fmaf(a0.z, v, acc[2]);  acc[3]  = fmaf(a0.w, v, acc[3]);
    acc[4]  = fmaf(a1.x, v, acc[4]);  acc[5]  = fmaf(a1.y, v, acc[5]);
    acc[6]  = fmaf(a1.z, v, acc[6]);  acc[7]  = fmaf(a1.w, v, acc[7]);
    acc[8]  = fmaf(a2.x, v, acc[8]);  acc[9]  = fmaf(a2.y, v, acc[9]);
    acc[10] = fmaf(a2.z, v, acc[10]); acc[11] = fmaf(a2.w, v, acc[11]);
    acc[12] = fmaf(a3.x, v, acc[12]); acc[13] = fmaf(a3.y, v, acc[13]);
    acc[14] = fmaf(a3.z, v, acc[14]); acc[15] = fmaf(a3.w, v, acc[15]);
  }

  float* pp = part + (size_t)sc * kB * kQ * kH;
#pragma unroll
  for (int i = 0; i < 16; i++)
    pp[(size_t)(b * kQ + q0 + i) * kH + h] = acc[i];
}

// ctx[i] = sum over 8 s-chunk partials
__global__ __launch_bounds__(256) void reduce_kernel(
    const float* __restrict__ part, float* __restrict__ ctx) {
  const int i = blockIdx.x * 256 + threadIdx.x;  // float4 index, 32768 total
  float4 a = {0, 0, 0, 0};
#pragma unroll
  for (int p = 0; p < 8; p++) {
    float4 v = ((const float4*)(part + (size_t)p * kB * kQ * kH))[i];
    a.x += v.x; a.y += v.y; a.z += v.z; a.w += v.w;
  }
  ((float4*)ctx)[i] = a;
}

extern "C" void kernel_launch(void* const* d_in, const int* in_sizes, int n_in,
                              void* d_out, int out_size, void* d_ws,
                              size_t ws_size, hipStream_t stream) {
  const float* query = (const float*)d_in[0];
  const float* key_  = (const float*)d_in[1];
  const float* value = (const float*)d_in[2];
  const float* Wq    = (const float*)d_in[3];
  const float* bq    = (const float*)d_in[4];
  const float* Wk    = (const float*)d_in[5];
  const float* bk    = (const float*)d_in[6];
  const float* we    = (const float*)d_in[7];
  // be (d_in[8]) cancels in softmax; weights/context are unaffected.

  float* ctx  = (float*)d_out;                         // [256*512]
  float* wout = (float*)d_out + (size_t)kB * kQ * kH;  // [256*1024]

  float* qp   = (float*)d_ws;                          // 512 KB
  float* kp   = qp + (size_t)kB * kQ * kH;             // 8 MB
  float* part = kp;                                    // aliases kp (dead after score)

  proj_dual<<<dim3(8, 68), 256, 0, stream>>>(key_, Wk, bk, kp, query, Wq, bq, qp);
  score_kernel<<<1024, 256, 0, stream>>>(qp, kp, we, wout);
  softmax_kernel<<<kB * kQ, 256, 0, stream>>>(wout);
  context_kernel<<<256, 256, 0, stream>>>(wout, value, part);
  reduce_kernel<<<kB * kQ * kH / 4 / 256, 256, 0, stream>>>(part, ctx);
}

// Round 3
// 203.572 us; speedup vs baseline: 1.4800x; 1.3228x over previous
//
#include <hip/hip_runtime.h>

// SoftAttention: B=4, Q=64, S=1024, H=512, fp32.
// out = [context (B*Q*H)] ++ [weights (B*Q*S)]
// ws layout: qp [256*512] at 0; kp [4096*512] at +512KB;
//            context partials [8][256*512] alias the (dead-after-score) kp region.

constexpr int kB = 4;
constexpr int kQ = 64;
constexpr int kS = 1024;
constexpr int kH = 512;

// ---------------------------------------------------------------------------
// Projection: Y[M,512] = X[M,512] @ W[512,512] + bias.
// 64x64 tile, 256 thr, 4x4 acc/thread. Both operands staged in LDS,
// double-buffered K-chunks of 64, register prefetch.
// grid = (8 col-tiles, 68 row-tiles: 64 kp + 4 qp)
// ---------------------------------------------------------------------------
constexpr int kLdsStride = 68;  // 64 + 4: 16B-aligned float4s, low bank aliasing

__global__ __launch_bounds__(256) void proj_dual(
    const float* __restrict__ Xk, const float* __restrict__ Wk,
    const float* __restrict__ bk, float* __restrict__ Yk,
    const float* __restrict__ Xq, const float* __restrict__ Wq,
    const float* __restrict__ bq, float* __restrict__ Yq) {
  __shared__ __align__(16) float As[2][64 * kLdsStride];  // [k][row]
  __shared__ __align__(16) float Bs[2][64 * kLdsStride];  // [k][col]
  const int t = threadIdx.x;
  const int ct = blockIdx.x;  // 0..7
  int rt = blockIdx.y;        // 0..67
  const float *X, *W, *bias;
  float* Y;
  if (rt < 64) {
    X = Xk + (size_t)rt * 64 * kH; W = Wk; bias = bk; Y = Yk + (size_t)rt * 64 * kH;
  } else {
    rt -= 64;
    X = Xq + (size_t)rt * 64 * kH; W = Wq; bias = bq; Y = Yq + (size_t)rt * 64 * kH;
  }

  // A staging mapping: row = t&63, kseg = (t>>6)*16  (4 float4 per thread)
  const int a_row = t & 63;
  const int a_k0 = (t >> 6) * 16;
  // B staging mapping: 4 passes; pass p: k = p*16 + (t>>4), c = (t&15)*4
  const int b_kl = t >> 4;        // 0..15
  const int b_c = (t & 15) * 4;   // 0..60
  const int cbase = ct * 64;

  // Compute mapping
  const int r0 = (t >> 4) * 4;   // 4 output rows
  const int c0 = (t & 15) * 4;   // 4 output cols

  float4 pa[4], pb[4];

  auto gload = [&](int kb) {
    const float* xp = X + (size_t)a_row * kH + kb + a_k0;
    pa[0] = *(const float4*)(xp + 0);
    pa[1] = *(const float4*)(xp + 4);
    pa[2] = *(const float4*)(xp + 8);
    pa[3] = *(const float4*)(xp + 12);
#pragma unroll
    for (int p = 0; p < 4; p++) {
      pb[p] = *(const float4*)(W + (size_t)(kb + p * 16 + b_kl) * kH + cbase + b_c);
    }
  };

  auto lwrite = [&](int buf) {
    float* a = As[buf];
#pragma unroll
    for (int j = 0; j < 4; j++) {
      a[(a_k0 + 4 * j + 0) * kLdsStride + a_row] = pa[j].x;
      a[(a_k0 + 4 * j + 1) * kLdsStride + a_row] = pa[j].y;
      a[(a_k0 + 4 * j + 2) * kLdsStride + a_row] = pa[j].z;
      a[(a_k0 + 4 * j + 3) * kLdsStride + a_row] = pa[j].w;
    }
    float* b = Bs[buf];
#pragma unroll
    for (int p = 0; p < 4; p++) {
      *(float4*)(b + (p * 16 + b_kl) * kLdsStride + b_c) = pb[p];
    }
  };

  float4 acc0 = {0,0,0,0}, acc1 = {0,0,0,0}, acc2 = {0,0,0,0}, acc3 = {0,0,0,0};

  gload(0);
  lwrite(0);
  __syncthreads();

  for (int kc = 0; kc < 8; kc++) {
    if (kc < 7) gload((kc + 1) * 64);

    const float* a = As[kc & 1];
    const float* b = Bs[kc & 1];
#pragma unroll 8
    for (int kk = 0; kk < 64; kk++) {
      float4 av = *(const float4*)(a + kk * kLdsStride + r0);
      float4 bv = *(const float4*)(b + kk * kLdsStride + c0);
      acc0.x = fmaf(av.x, bv.x, acc0.x); acc0.y = fmaf(av.x, bv.y, acc0.y);
      acc0.z = fmaf(av.x, bv.z, acc0.z); acc0.w = fmaf(av.x, bv.w, acc0.w);
      acc1.x = fmaf(av.y, bv.x, acc1.x); acc1.y = fmaf(av.y, bv.y, acc1.y);
      acc1.z = fmaf(av.y, bv.z, acc1.z); acc1.w = fmaf(av.y, bv.w, acc1.w);
      acc2.x = fmaf(av.z, bv.x, acc2.x); acc2.y = fmaf(av.z, bv.y, acc2.y);
      acc2.z = fmaf(av.z, bv.z, acc2.z); acc2.w = fmaf(av.z, bv.w, acc2.w);
      acc3.x = fmaf(av.w, bv.x, acc3.x); acc3.y = fmaf(av.w, bv.y, acc3.y);
      acc3.z = fmaf(av.w, bv.z, acc3.z); acc3.w = fmaf(av.w, bv.w, acc3.w);
    }

    if (kc < 7) {
      __syncthreads();           // everyone done computing on buf[kc&1]
      lwrite((kc + 1) & 1);
      __syncthreads();           // next buffer ready
    }
  }

  float4 bv = *(const float4*)(bias + cbase + c0);
  acc0.x += bv.x; acc0.y += bv.y; acc0.z += bv.z; acc0.w += bv.w;
  acc1.x += bv.x; acc1.y += bv.y; acc1.z += bv.z; acc1.w += bv.w;
  acc2.x += bv.x; acc2.y += bv.y; acc2.z += bv.z; acc2.w += bv.w;
  acc3.x += bv.x; acc3.y += bv.y; acc3.z += bv.z; acc3.w += bv.w;
  float* yp = Y + (size_t)r0 * kH + cbase + c0;
  *(float4*)(yp + 0 * kH) = acc0;
  *(float4*)(yp + 1 * kH) = acc1;
  *(float4*)(yp + 2 * kH) = acc2;
  *(float4*)(yp + 3 * kH) = acc3;
}

// ---------------------------------------------------------------------------
// Scores: raw (un-softmaxed) scores -> sout[bq][s].  be is dropped (cancels in
// softmax).  grid = 1024 (b x 16 q-tiles x 16 s-chunks), 256 thr = 4 waves.
// tanh(x) = 1 - 2*d, d = rcp(1 + exp(2x));  sum we*tanh = sum_we - 2*sum we*d.
// ---------------------------------------------------------------------------
__global__ __launch_bounds__(256) void score_kernel(
    const float* __restrict__ qp, const float* __restrict__ kp,
    const float* __restrict__ we, float* __restrict__ sout) {
  const int bx = blockIdx.x;
  const int b = bx >> 8, qt = (bx >> 4) & 15, st = bx & 15;
  const int t = threadIdx.x, wave = t >> 6, lane = t & 63;

  const float4* we4 = (const float4*)(we + lane * 8);
  const float4 w0 = we4[0], w1 = we4[1];
  float wsum = w0.x + w0.y + w0.z + w0.w + w1.x + w1.y + w1.z + w1.w;
#pragma unroll
  for (int off = 32; off; off >>= 1) wsum += __shfl_xor(wsum, off);

  const int q0 = qt * 4;
  float4 qv[4][2];
#pragma unroll
  for (int i = 0; i < 4; i++) {
    const float4* q4 = (const float4*)(qp + (size_t)(b * kQ + q0 + i) * kH + lane * 8);
    qv[i][0] = q4[0]; qv[i][1] = q4[1];
  }

  const float* kpb = kp + (size_t)b * kS * kH;
  const int sbase = st * 64 + wave * 16;

  for (int si = 0; si < 16; si++) {
    const int s = sbase + si;
    const float4* k4 = (const float4*)(kpb + (size_t)s * kH + lane * 8);
    float4 k0 = k4[0], k1 = k4[1];
    float a[4];
#pragma unroll
    for (int i = 0; i < 4; i++) {
      float acc = 0.f;
      float e;
      e = __expf(2.f * (qv[i][0].x + k0.x)); acc = fmaf(w0.x, __builtin_amdgcn_rcpf(1.f + e), acc);
      e = __expf(2.f * (qv[i][0].y + k0.y)); acc = fmaf(w0.y, __builtin_amdgcn_rcpf(1.f + e), acc);
      e = __expf(2.f * (qv[i][0].z + k0.z)); acc = fmaf(w0.z, __builtin_amdgcn_rcpf(1.f + e), acc);
      e = __expf(2.f * (qv[i][0].w + k0.w)); acc = fmaf(w0.w, __builtin_amdgcn_rcpf(1.f + e), acc);
      e = __expf(2.f * (qv[i][1].x + k1.x)); acc = fmaf(w1.x, __builtin_amdgcn_rcpf(1.f + e), acc);
      e = __expf(2.f * (qv[i][1].y + k1.y)); acc = fmaf(w1.y, __builtin_amdgcn_rcpf(1.f + e), acc);
      e = __expf(2.f * (qv[i][1].z + k1.z)); acc = fmaf(w1.z, __builtin_amdgcn_rcpf(1.f + e), acc);
      e = __expf(2.f * (qv[i][1].w + k1.w)); acc = fmaf(w1.w, __builtin_amdgcn_rcpf(1.f + e), acc);
      a[i] = acc;
    }
#pragma unroll
    for (int i = 0; i < 4; i++) {
#pragma unroll
      for (int off = 32; off; off >>= 1) a[i] += __shfl_xor(a[i], off);
    }
    if (lane == 0) {
#pragma unroll
      for (int i = 0; i < 4; i++)
        sout[(size_t)(b * kQ + q0 + i) * kS + s] = fmaf(-2.f, a[i], wsum);
    }
  }
}

// ---------------------------------------------------------------------------
// Softmax in place on wout rows of 1024.  grid = 256 rows, 256 thr (4 waves).
// ---------------------------------------------------------------------------
__global__ __launch_bounds__(256) void softmax_kernel(float* __restrict__ wout) {
  __shared__ float redm[4];
  __shared__ float reds[4];
  const int row = blockIdx.x;
  const int t = threadIdx.x, wave = t >> 6, lane = t & 63;
  float4* rp = (float4*)(wout + (size_t)row * kS);
  float4 v = rp[t];

  float m = fmaxf(fmaxf(v.x, v.y), fmaxf(v.z, v.w));
#pragma unroll
  for (int off = 32; off; off >>= 1) m = fmaxf(m, __shfl_xor(m, off));
  if (lane == 0) redm[wave] = m;
  __syncthreads();
  m = fmaxf(fmaxf(redm[0], redm[1]), fmaxf(redm[2], redm[3]));

  float4 e;
  e.x = __expf(v.x - m); e.y = __expf(v.y - m);
  e.z = __expf(v.z - m); e.w = __expf(v.w - m);
  float sum = e.x + e.y + e.z + e.w;
#pragma unroll
  for (int off = 32; off; off >>= 1) sum += __shfl_xor(sum, off);
  if (lane == 0) reds[wave] = sum;
  __syncthreads();
  sum = reds[0] + reds[1] + reds[2] + reds[3];
  float inv = 1.f / sum;
  e.x *= inv; e.y *= inv; e.z *= inv; e.w *= inv;
  rp[t] = e;
}

// ---------------------------------------------------------------------------
// Context partials: part[sc][bq][h] = sum_{s in chunk} w[bq][s] * value[b][s][h]
// grid = 256 (b x 2 h-chunks x 4 q-chunks x 8 s-chunks), 256 thr.
// ---------------------------------------------------------------------------
__global__ __launch_bounds__(256) void context_kernel(
    const float* __restrict__ wout, const float* __restrict__ value,
    float* __restrict__ part) {
  __shared__ __align__(16) float wt[128][16];
  const int bx = blockIdx.x;
  const int sc = bx & 7, qc = (bx >> 3) & 3, hc = (bx >> 5) & 1, b = bx >> 6;
  const int t = threadIdx.x;
  const int s0 = sc * 128, q0 = qc * 16;

  {
    const int q_l = t & 15;
    const int sseg = (t >> 4) * 8;
    const float4* p4 =
        (const float4*)(wout + (size_t)(b * kQ + q0 + q_l) * kS + s0 + sseg);
    float4 u0 = p4[0], u1 = p4[1];
    wt[sseg + 0][q_l] = u0.x; wt[sseg + 1][q_l] = u0.y;
    wt[sseg + 2][q_l] = u0.z; wt[sseg + 3][q_l] = u0.w;
    wt[sseg + 4][q_l] = u1.x; wt[sseg + 5][q_l] = u1.y;
    wt[sseg + 6][q_l] = u1.z; wt[sseg + 7][q_l] = u1.w;
  }
  __syncthreads();

  const int h = hc * 256 + t;
  const float* vb = value + ((size_t)b * kS + s0) * kH + h;
  float acc[16];
#pragma unroll
  for (int i = 0; i < 16; i++) acc[i] = 0.f;

#pragma unroll 4
  for (int s = 0; s < 128; s++) {
    float v = vb[(size_t)s * kH];
    const float4* wrow = (const float4*)&wt[s][0];
    float4 a0 = wrow[0], a1 = wrow[1], a2 = wrow[2], a3 = wrow[3];
    acc[0]  = fmaf(a0.x, v, acc[0]);  acc[1]  = fmaf(a0.y, v, acc[1]);
    acc[2]  = fmaf(a0.z, v, acc[2]);  acc[3]  = fmaf(a0.w, v, acc[3]);
    acc[4]  = fmaf(a1.x, v, acc[4]);  acc[5]  = fmaf(a1.y, v, acc[5]);
    acc[6]  = fmaf(a1.z, v, acc[6]);  acc[7]  = fmaf(a1.w, v, acc[7]);
    acc[8]  = fmaf(a2.x, v, acc[8]);  acc[9]  = fmaf(a2.y, v, acc[9]);
    acc[10] = fmaf(a2.z, v, acc[10]); acc[11] = fmaf(a2.w, v, acc[11]);
    acc[12] = fmaf(a3.x, v, acc[12]); acc[13] = fmaf(a3.y, v, acc[13]);
    acc[14] = fmaf(a3.z, v, acc[14]); acc[15] = fmaf(a3.w, v, acc[15]);
  }

  float* pp = part + (size_t)sc * kB * kQ * kH;
#pragma unroll
  for (int i = 0; i < 16; i++)
    pp[(size_t)(b * kQ + q0 + i) * kH + h] = acc[i];
}

// ctx[i] = sum over 8 s-chunk partials
__global__ __launch_bounds__(256) void reduce_kernel(
    const float* __restrict__ part, float* __restrict__ ctx) {
  const int i = blockIdx.x * 256 + threadIdx.x;
  float4 a = {0, 0, 0, 0};
#pragma unroll
  for (int p = 0; p < 8; p++) {
    float4 v = ((const float4*)(part + (size_t)p * kB * kQ * kH))[i];
    a.x += v.x; a.y += v.y; a.z += v.z; a.w += v.w;
  }
  ((float4*)ctx)[i] = a;
}

extern "C" void kernel_launch(void* const* d_in, const int* in_sizes, int n_in,
                              void* d_out, int out_size, void* d_ws,
                              size_t ws_size, hipStream_t stream) {
  const float* query = (const float*)d_in[0];
  const float* key_  = (const float*)d_in[1];
  const float* value = (const float*)d_in[2];
  const float* Wq    = (const float*)d_in[3];
  const float* bq    = (const float*)d_in[4];
  const float* Wk    = (const float*)d_in[5];
  const float* bk    = (const float*)d_in[6];
  const float* we    = (const float*)d_in[7];
  // be (d_in[8]) cancels in softmax.

  float* ctx  = (float*)d_out;                         // [256*512]
  float* wout = (float*)d_out + (size_t)kB * kQ * kH;  // [256*1024]

  float* qp   = (float*)d_ws;                          // 512 KB
  float* kp   = qp + (size_t)kB * kQ * kH;             // 8 MB
  float* part = kp;                                    // aliases kp (dead after score)

  proj_dual<<<dim3(8, 68), 256, 0, stream>>>(key_, Wk, bk, kp, query, Wq, bq, qp);
  score_kernel<<<1024, 256, 0, stream>>>(qp, kp, we, wout);
  softmax_kernel<<<kB * kQ, 256, 0, stream>>>(wout);
  context_kernel<<<256, 256, 0, stream>>>(wout, value, part);
  reduce_kernel<<<kB * kQ * kH / 4 / 256, 256, 0, stream>>>(part, ctx);
}

// Round 4
// 186.185 us; speedup vs baseline: 1.6182x; 1.0934x over previous
//
#include <hip/hip_runtime.h>

// SoftAttention: B=4, Q=64, S=1024, H=512, fp32.
// out = [context (B*Q*H)] ++ [weights (B*Q*S)]
// ws: qp [256*512] at 0; kp [4096*512] at +512KB; partials alias kp.
// NOTE: proj writes 2*(X@W + b) — score uses only exp(2*(q+k)); be cancels.

constexpr int kB = 4;
constexpr int kQ = 64;
constexpr int kS = 1024;
constexpr int kH = 512;

// ---------------------------------------------------------------------------
// Projection: Y = 2*(X[M,512] @ W[512,512] + bias).
// 64x64 tile, 256 thr, 4x4 acc/thread, K-chunks of 32, double-buffered LDS
// (34 KB -> 4 blocks/CU = 4 waves/SIMD for latency hiding).
// grid = (8 col-tiles, 68 row-tiles: 64 kp + 4 qp)
// ---------------------------------------------------------------------------
constexpr int kLdsStride = 68;

__global__ __launch_bounds__(256, 4) void proj_dual(
    const float* __restrict__ Xk, const float* __restrict__ Wk,
    const float* __restrict__ bk, float* __restrict__ Yk,
    const float* __restrict__ Xq, const float* __restrict__ Wq,
    const float* __restrict__ bq, float* __restrict__ Yq) {
  __shared__ __align__(16) float As[2][32 * kLdsStride];  // [k][row]
  __shared__ __align__(16) float Bs[2][32 * kLdsStride];  // [k][col]
  const int t = threadIdx.x;
  const int ct = blockIdx.x;  // 0..7
  int rt = blockIdx.y;        // 0..67
  const float *X, *W, *bias;
  float* Y;
  if (rt < 64) {
    X = Xk + (size_t)rt * 64 * kH; W = Wk; bias = bk; Y = Yk + (size_t)rt * 64 * kH;
  } else {
    rt -= 64;
    X = Xq + (size_t)rt * 64 * kH; W = Wq; bias = bq; Y = Yq + (size_t)rt * 64 * kH;
  }

  // A staging: row = t&63, k0 = (t>>6)*8, 2 float4/thread (transposed into LDS)
  const int a_row = t & 63;
  const int a_k0 = (t >> 6) * 8;
  // B staging: pass p in {0,1}: k = p*16 + (t>>4), c = (t&15)*4
  const int b_kl = t >> 4;
  const int b_c = (t & 15) * 4;
  const int cbase = ct * 64;
  // Compute mapping: 4 rows x 4 cols per thread
  const int r0 = (t >> 4) * 4;
  const int c0 = (t & 15) * 4;

  float4 pa[2], pb[2];

  auto gload = [&](int kb) {
    const float* xp = X + (size_t)a_row * kH + kb + a_k0;
    pa[0] = *(const float4*)(xp + 0);
    pa[1] = *(const float4*)(xp + 4);
#pragma unroll
    for (int p = 0; p < 2; p++)
      pb[p] = *(const float4*)(W + (size_t)(kb + p * 16 + b_kl) * kH + cbase + b_c);
  };

  auto lwrite = [&](int buf) {
    float* a = As[buf];
#pragma unroll
    for (int j = 0; j < 2; j++) {
      a[(a_k0 + 4 * j + 0) * kLdsStride + a_row] = pa[j].x;
      a[(a_k0 + 4 * j + 1) * kLdsStride + a_row] = pa[j].y;
      a[(a_k0 + 4 * j + 2) * kLdsStride + a_row] = pa[j].z;
      a[(a_k0 + 4 * j + 3) * kLdsStride + a_row] = pa[j].w;
    }
    float* b = Bs[buf];
#pragma unroll
    for (int p = 0; p < 2; p++)
      *(float4*)(b + (p * 16 + b_kl) * kLdsStride + b_c) = pb[p];
  };

  float4 acc0 = {0,0,0,0}, acc1 = {0,0,0,0}, acc2 = {0,0,0,0}, acc3 = {0,0,0,0};

  gload(0);
  lwrite(0);
  __syncthreads();

  for (int kc = 0; kc < 16; kc++) {
    if (kc < 15) gload((kc + 1) * 32);

    const float* a = As[kc & 1];
    const float* b = Bs[kc & 1];
#pragma unroll 8
    for (int kk = 0; kk < 32; kk++) {
      float4 av = *(const float4*)(a + kk * kLdsStride + r0);
      float4 bv = *(const float4*)(b + kk * kLdsStride + c0);
      acc0.x = fmaf(av.x, bv.x, acc0.x); acc0.y = fmaf(av.x, bv.y, acc0.y);
      acc0.z = fmaf(av.x, bv.z, acc0.z); acc0.w = fmaf(av.x, bv.w, acc0.w);
      acc1.x = fmaf(av.y, bv.x, acc1.x); acc1.y = fmaf(av.y, bv.y, acc1.y);
      acc1.z = fmaf(av.y, bv.z, acc1.z); acc1.w = fmaf(av.y, bv.w, acc1.w);
      acc2.x = fmaf(av.z, bv.x, acc2.x); acc2.y = fmaf(av.z, bv.y, acc2.y);
      acc2.z = fmaf(av.z, bv.z, acc2.z); acc2.w = fmaf(av.z, bv.w, acc2.w);
      acc3.x = fmaf(av.w, bv.x, acc3.x); acc3.y = fmaf(av.w, bv.y, acc3.y);
      acc3.z = fmaf(av.w, bv.z, acc3.z); acc3.w = fmaf(av.w, bv.w, acc3.w);
    }

    if (kc < 15) {
      __syncthreads();
      lwrite((kc + 1) & 1);
      __syncthreads();
    }
  }

  // Y = 2*(acc + bias)
  float4 bv = *(const float4*)(bias + cbase + c0);
  float* yp = Y + (size_t)r0 * kH + cbase + c0;
  float4 o;
  o.x = 2.f*(acc0.x+bv.x); o.y = 2.f*(acc0.y+bv.y); o.z = 2.f*(acc0.z+bv.z); o.w = 2.f*(acc0.w+bv.w);
  *(float4*)(yp + 0 * kH) = o;
  o.x = 2.f*(acc1.x+bv.x); o.y = 2.f*(acc1.y+bv.y); o.z = 2.f*(acc1.z+bv.z); o.w = 2.f*(acc1.w+bv.w);
  *(float4*)(yp + 1 * kH) = o;
  o.x = 2.f*(acc2.x+bv.x); o.y = 2.f*(acc2.y+bv.y); o.z = 2.f*(acc2.z+bv.z); o.w = 2.f*(acc2.w+bv.w);
  *(float4*)(yp + 2 * kH) = o;
  o.x = 2.f*(acc3.x+bv.x); o.y = 2.f*(acc3.y+bv.y); o.z = 2.f*(acc3.z+bv.z); o.w = 2.f*(acc3.w+bv.w);
  *(float4*)(yp + 3 * kH) = o;
}

// ---------------------------------------------------------------------------
// Scores (raw) -> sout[bq][s].  qp/kp hold 2*(proj); be cancels in softmax.
// tanh(x) = 1 - 2*rcp(1+exp(2x));  sum we*tanh = sum_we + sum (-2*we)*rcp(...)
// grid = 1024 (b x 16 q-tiles x 16 s-chunks), 256 thr = 4 waves, 16 s/wave.
// ---------------------------------------------------------------------------
__global__ __launch_bounds__(256) void score_kernel(
    const float* __restrict__ qp, const float* __restrict__ kp,
    const float* __restrict__ we, float* __restrict__ sout) {
  const int bx = blockIdx.x;
  const int b = bx >> 8, qt = (bx >> 4) & 15, st = bx & 15;
  const int t = threadIdx.x, wave = t >> 6, lane = t & 63;

  const float4* we4 = (const float4*)(we + lane * 8);
  float4 w0 = we4[0], w1 = we4[1];
  float wsum = w0.x + w0.y + w0.z + w0.w + w1.x + w1.y + w1.z + w1.w;
#pragma unroll
  for (int off = 32; off; off >>= 1) wsum += __shfl_xor(wsum, off);
  // fold the -2 of tanh into the weights
  w0.x *= -2.f; w0.y *= -2.f; w0.z *= -2.f; w0.w *= -2.f;
  w1.x *= -2.f; w1.y *= -2.f; w1.z *= -2.f; w1.w *= -2.f;

  const int q0 = qt * 4;
  float4 qv[4][2];
#pragma unroll
  for (int i = 0; i < 4; i++) {
    const float4* q4 = (const float4*)(qp + (size_t)(b * kQ + q0 + i) * kH + lane * 8);
    qv[i][0] = q4[0]; qv[i][1] = q4[1];
  }

  const int sbase = st * 64 + wave * 16;
  const float* kbase = kp + ((size_t)b * kS + sbase) * kH + lane * 8;

  float4 k0 = *(const float4*)(kbase);
  float4 k1 = *(const float4*)(kbase + 4);

  for (int si = 0; si < 16; si++) {
    float4 n0, n1;
    if (si < 15) {
      const float* np = kbase + (size_t)(si + 1) * kH;
      n0 = *(const float4*)(np);
      n1 = *(const float4*)(np + 4);
    }
    float a[4];
#pragma unroll
    for (int i = 0; i < 4; i++) {
      float acc = 0.f, e;
      e = __expf(qv[i][0].x + k0.x); acc = fmaf(w0.x, __builtin_amdgcn_rcpf(1.f + e), acc);
      e = __expf(qv[i][0].y + k0.y); acc = fmaf(w0.y, __builtin_amdgcn_rcpf(1.f + e), acc);
      e = __expf(qv[i][0].z + k0.z); acc = fmaf(w0.z, __builtin_amdgcn_rcpf(1.f + e), acc);
      e = __expf(qv[i][0].w + k0.w); acc = fmaf(w0.w, __builtin_amdgcn_rcpf(1.f + e), acc);
      e = __expf(qv[i][1].x + k1.x); acc = fmaf(w1.x, __builtin_amdgcn_rcpf(1.f + e), acc);
      e = __expf(qv[i][1].y + k1.y); acc = fmaf(w1.y, __builtin_amdgcn_rcpf(1.f + e), acc);
      e = __expf(qv[i][1].z + k1.z); acc = fmaf(w1.z, __builtin_amdgcn_rcpf(1.f + e), acc);
      e = __expf(qv[i][1].w + k1.w); acc = fmaf(w1.w, __builtin_amdgcn_rcpf(1.f + e), acc);
      a[i] = acc;
    }
#pragma unroll
    for (int i = 0; i < 4; i++) {
#pragma unroll
      for (int off = 32; off; off >>= 1) a[i] += __shfl_xor(a[i], off);
    }
    if (lane == 0) {
      const int s = sbase + si;
#pragma unroll
      for (int i = 0; i < 4; i++)
        sout[(size_t)(b * kQ + q0 + i) * kS + s] = a[i] + wsum;
    }
    k0 = n0; k1 = n1;
  }
}

// ---------------------------------------------------------------------------
// Softmax in place on wout rows of 1024.  grid = 256 rows, 256 thr.
// ---------------------------------------------------------------------------
__global__ __launch_bounds__(256) void softmax_kernel(float* __restrict__ wout) {
  __shared__ float redm[4];
  __shared__ float reds[4];
  const int row = blockIdx.x;
  const int t = threadIdx.x, wave = t >> 6, lane = t & 63;
  float4* rp = (float4*)(wout + (size_t)row * kS);
  float4 v = rp[t];

  float m = fmaxf(fmaxf(v.x, v.y), fmaxf(v.z, v.w));
#pragma unroll
  for (int off = 32; off; off >>= 1) m = fmaxf(m, __shfl_xor(m, off));
  if (lane == 0) redm[wave] = m;
  __syncthreads();
  m = fmaxf(fmaxf(redm[0], redm[1]), fmaxf(redm[2], redm[3]));

  float4 e;
  e.x = __expf(v.x - m); e.y = __expf(v.y - m);
  e.z = __expf(v.z - m); e.w = __expf(v.w - m);
  float sum = e.x + e.y + e.z + e.w;
#pragma unroll
  for (int off = 32; off; off >>= 1) sum += __shfl_xor(sum, off);
  if (lane == 0) reds[wave] = sum;
  __syncthreads();
  sum = reds[0] + reds[1] + reds[2] + reds[3];
  float inv = 1.f / sum;
  e.x *= inv; e.y *= inv; e.z *= inv; e.w *= inv;
  rp[t] = e;
}

// ---------------------------------------------------------------------------
// Context partials: part[sc][bq][h] = sum_{s in chunk} w[bq][s] * value[b][s][h]
// grid = 256 (b x 2 h-chunks x 4 q-chunks x 8 s-chunks), 256 thr.
// ---------------------------------------------------------------------------
__global__ __launch_bounds__(256) void context_kernel(
    const float* __restrict__ wout, const float* __restrict__ value,
    float* __restrict__ part) {
  __shared__ __align__(16) float wt[128][16];
  const int bx = blockIdx.x;
  const int sc = bx & 7, qc = (bx >> 3) & 3, hc = (bx >> 5) & 1, b = bx >> 6;
  const int t = threadIdx.x;
  const int s0 = sc * 128, q0 = qc * 16;

  {
    const int q_l = t & 15;
    const int sseg = (t >> 4) * 8;
    const float4* p4 =
        (const float4*)(wout + (size_t)(b * kQ + q0 + q_l) * kS + s0 + sseg);
    float4 u0 = p4[0], u1 = p4[1];
    wt[sseg + 0][q_l] = u0.x; wt[sseg + 1][q_l] = u0.y;
    wt[sseg + 2][q_l] = u0.z; wt[sseg + 3][q_l] = u0.w;
    wt[sseg + 4][q_l] = u1.x; wt[sseg + 5][q_l] = u1.y;
    wt[sseg + 6][q_l] = u1.z; wt[sseg + 7][q_l] = u1.w;
  }
  __syncthreads();

  const int h = hc * 256 + t;
  const float* vb = value + ((size_t)b * kS + s0) * kH + h;
  float acc[16];
#pragma unroll
  for (int i = 0; i < 16; i++) acc[i] = 0.f;

#pragma unroll 4
  for (int s = 0; s < 128; s++) {
    float v = vb[(size_t)s * kH];
    const float4* wrow = (const float4*)&wt[s][0];
    float4 a0 = wrow[0], a1 = wrow[1], a2 = wrow[2], a3 = wrow[3];
    acc[0]  = fmaf(a0.x, v, acc[0]);  acc[1]  = fmaf(a0.y, v, acc[1]);
    acc[2]  = fmaf(a0.z, v, acc[2]);  acc[3]  = fmaf(a0.w, v, acc[3]);
    acc[4]  = fmaf(a1.x, v, acc[4]);  acc[5]  = fmaf(a1.y, v, acc[5]);
    acc[6]  = fmaf(a1.z, v, acc[6]);  acc[7]  = fmaf(a1.w, v, acc[7]);
    acc[8]  = fmaf(a2.x, v, acc[8]);  acc[9]  = fmaf(a2.y, v, acc[9]);
    acc[10] = fmaf(a2.z, v, acc[10]); acc[11] = fmaf(a2.w, v, acc[11]);
    acc[12] = fmaf(a3.x, v, acc[12]); acc[13] = fmaf(a3.y, v, acc[13]);
    acc[14] = fmaf(a3.z, v, acc[14]); acc[15] = fmaf(a3.w, v, acc[15]);
  }

  float* pp = part + (size_t)sc * kB * kQ * kH;
#pragma unroll
  for (int i = 0; i < 16; i++)
    pp[(size_t)(b * kQ + q0 + i) * kH + h] = acc[i];
}

// ctx[i] = sum over 8 s-chunk partials
__global__ __launch_bounds__(256) void reduce_kernel(
    const float* __restrict__ part, float* __restrict__ ctx) {
  const int i = blockIdx.x * 256 + threadIdx.x;
  float4 a = {0, 0, 0, 0};
#pragma unroll
  for (int p = 0; p < 8; p++) {
    float4 v = ((const float4*)(part + (size_t)p * kB * kQ * kH))[i];
    a.x += v.x; a.y += v.y; a.z += v.z; a.w += v.w;
  }
  ((float4*)ctx)[i] = a;
}

extern "C" void kernel_launch(void* const* d_in, const int* in_sizes, int n_in,
                              void* d_out, int out_size, void* d_ws,
                              size_t ws_size, hipStream_t stream) {
  const float* query = (const float*)d_in[0];
  const float* key_  = (const float*)d_in[1];
  const float* value = (const float*)d_in[2];
  const float* Wq    = (const float*)d_in[3];
  const float* bq    = (const float*)d_in[4];
  const float* Wk    = (const float*)d_in[5];
  const float* bk    = (const float*)d_in[6];
  const float* we    = (const float*)d_in[7];
  // be (d_in[8]) cancels in softmax.

  float* ctx  = (float*)d_out;                         // [256*512]
  float* wout = (float*)d_out + (size_t)kB * kQ * kH;  // [256*1024]

  float* qp   = (float*)d_ws;                          // 512 KB
  float* kp   = qp + (size_t)kB * kQ * kH;             // 8 MB
  float* part = kp;                                    // aliases kp (dead after score)

  proj_dual<<<dim3(8, 68), 256, 0, stream>>>(key_, Wk, bk, kp, query, Wq, bq, qp);
  score_kernel<<<1024, 256, 0, stream>>>(qp, kp, we, wout);
  softmax_kernel<<<kB * kQ, 256, 0, stream>>>(wout);
  context_kernel<<<256, 256, 0, stream>>>(wout, value, part);
  reduce_kernel<<<kB * kQ * kH / 4 / 256, 256, 0, stream>>>(part, ctx);
}